// Round 1
// baseline (475.715 us; speedup 1.0000x reference)
//
#include <hip/hip_runtime.h>

#define HW   3136   // 56*56
#define HW4  784    // HW/4
#define KSEL 313    // int(0.1 * 3136)
#define NT   256

// Count elements in LDS row with key >= v (block-wide, uniform result).
__device__ __forceinline__ unsigned block_count_ge(const unsigned* bits, unsigned v,
                                                   int tid, unsigned* red) {
  unsigned c = 0;
  for (int i = tid; i < HW; i += NT) c += ((bits[i] & 0x7FFFFFFFu) >= v) ? 1u : 0u;
#pragma unroll
  for (int off = 32; off > 0; off >>= 1) c += __shfl_xor(c, off);
  __syncthreads();                       // protect red from previous use
  if ((tid & 63) == 0) red[tid >> 6] = c;
  __syncthreads();
  return red[0] + red[1] + red[2] + red[3];
}

__global__ __launch_bounds__(NT, 8)
void topk_mask_kernel(const unsigned* __restrict__ x, unsigned* __restrict__ out) {
  __shared__ __align__(16) unsigned bits[HW];  // full fp32 bit patterns of the row
  __shared__ unsigned hist[256];
  __shared__ unsigned red[4];
  __shared__ unsigned sel[3];
  __shared__ unsigned glist[64];
  __shared__ unsigned gcnt;

  const int tid  = threadIdx.x;
  const int lane = tid & 63;
  const int wv   = tid >> 6;
  const size_t row = blockIdx.x;
  const unsigned* __restrict__ src = x + row * (size_t)HW;
  unsigned* __restrict__ dst = out + row * (size_t)HW;

  // ---- stage row into LDS (uint4) + init ----
  for (int i = tid; i < HW4; i += NT)
    reinterpret_cast<uint4*>(bits)[i] = reinterpret_cast<const uint4*>(src)[i];
  hist[tid] = 0u;
  if (tid == 0) { gcnt = 0u; sel[0] = 0xFFFFFFFFu; }
  __syncthreads();

  // ---- pass 1: linear-bucket histogram over |x| in [1.3, 2.0) ----
  // bucket 0  : |x| <  1.3  (below bracket, not counted — definitely below threshold)
  // bucket 255: |x| >= 2.0  (above bracket)
  // Per-row count in-bracket ~600, spread over 255 bins -> negligible atomic conflict.
  const float LB = 1.3f;
  const float SC = 254.0f / 0.7f;

  for (int i = tid; i < HW4; i += NT) {
    uint4 v = reinterpret_cast<const uint4*>(bits)[i];
#pragma unroll
    for (int j = 0; j < 4; ++j) {
      unsigned key = ((j == 0) ? v.x : (j == 1) ? v.y : (j == 2) ? v.z : v.w) & 0x7FFFFFFFu;
      float a = __uint_as_float(key);
      if (a >= LB) {
        float ac = fminf(a, 2.1f);              // overflow-safe, monotone
        int b = 1 + (int)((ac - LB) * SC);
        b = (b > 255) ? 255 : b;
        atomicAdd(&hist[b], 1u);
      }
    }
  }
  __syncthreads();

  // ---- suffix scan S[b] = count(bucket >= b), find crossing bin for kr ----
  const unsigned kr = KSEL;
  unsigned c  = (tid == 0) ? 0u : hist[tid];
  unsigned sv = c;
#pragma unroll
  for (int off = 1; off < 64; off <<= 1) {      // per-wave inclusive suffix scan
    unsigned u = __shfl_down(sv, off);
    if (lane + off < 64) sv += u;
  }
  if (lane == 0) red[wv] = sv;
  __syncthreads();
  unsigned S = sv;
  for (int w = wv + 1; w < 4; ++w) S += red[w];
  unsigned S1 = S - c;                          // S[tid+1]
  if (tid >= 1 && S >= kr && S1 < kr) {         // unique crossing bin
    sel[0] = (unsigned)tid;                     // b*
    sel[1] = kr - S1;                           // rank needed inside bin
  }
  __syncthreads();

  unsigned t = 0, need_eq = 0, cnt_eq = 0;
  bool fast = (sel[0] != 0xFFFFFFFFu);          // bracket valid?
  if (fast) {
    const unsigned bsel = sel[0];
    const unsigned krb  = sel[1];
    // ---- gather the threshold bin's members (expected 2-3) ----
    for (int i = tid; i < HW4; i += NT) {
      uint4 v = reinterpret_cast<const uint4*>(bits)[i];
#pragma unroll
      for (int j = 0; j < 4; ++j) {
        unsigned key = ((j == 0) ? v.x : (j == 1) ? v.y : (j == 2) ? v.z : v.w) & 0x7FFFFFFFu;
        float a = __uint_as_float(key);
        if (a >= LB) {
          float ac = fminf(a, 2.1f);
          int b = 1 + (int)((ac - LB) * SC);
          b = (b > 255) ? 255 : b;
          if ((unsigned)b == bsel) {
            unsigned p = atomicAdd(&gcnt, 1u);
            if (p < 64u) glist[p] = key;
          }
        }
      }
    }
    __syncthreads();
    const unsigned cnt = gcnt;
    if (cnt <= 64u) {
      // ---- wave 0: exact rank among bin members via shuffle broadcast ----
      if (tid < 64) {
        unsigned kv = (tid < (int)cnt) ? glist[tid] : 0u;
        unsigned gt = 0, eq = 0;
        for (int i = 0; i < (int)cnt; ++i) {
          unsigned u = __shfl(kv, i);
          gt += (u > kv) ? 1u : 0u;
          eq += (u == kv) ? 1u : 0u;
        }
        // kv is the krb-th largest iff gt < krb <= gt+eq (all such lanes hold same kv)
        if (tid < (int)cnt && gt < krb && gt + eq >= krb) {
          sel[0] = kv;          // exact threshold key t
          sel[1] = krb - gt;    // need_eq
          sel[2] = eq;          // cnt_eq (all equals are in this bin)
        }
      }
      __syncthreads();
      t = sel[0]; need_eq = sel[1]; cnt_eq = sel[2];
    } else {
      fast = false;
    }
  }

  if (!fast) {
    // ---- correct-for-anything fallback: bisection on the key space ----
    unsigned lo = 0u, hi = 0x80000000u;         // f(lo)=true, f(hi)=false
    while (hi - lo > 1u) {
      unsigned mid = lo + ((hi - lo) >> 1);
      unsigned cge = block_count_ge(bits, mid, tid, red);
      if (cge >= KSEL) lo = mid; else hi = mid;
    }
    t = lo;                                     // k-th largest key
    unsigned cge = block_count_ge(bits, t, tid, red);
    unsigned cgt = (t >= 0x7FFFFFFFu) ? 0u : block_count_ge(bits, t + 1u, tid, red);
    cnt_eq  = cge - cgt;
    need_eq = KSEL - cgt;
  }

  // ---- tie handling (stable: keep lowest-index equals, like lax.top_k) ----
  if (t == 0u) {
    t = 1u;  // zeros stay zero either way; avoids the equality path entirely
  } else if (cnt_eq != need_eq) {               // rare (~2 rows in 16384)
    __syncthreads();
    if (tid == 0) {
      unsigned seen = 0;
      for (int i = 0; i < HW; ++i) {
        if ((bits[i] & 0x7FFFFFFFu) == t) {
          ++seen;
          if (seen > need_eq) bits[i] = 0u;     // drop excess (highest-index) equals
        }
      }
    }
  }
  __syncthreads();

  // ---- output: keep iff |x| bits >= t ----
  for (int i = tid; i < HW4; i += NT) {
    uint4 v = reinterpret_cast<const uint4*>(bits)[i];
    v.x = ((v.x & 0x7FFFFFFFu) >= t) ? v.x : 0u;
    v.y = ((v.y & 0x7FFFFFFFu) >= t) ? v.y : 0u;
    v.z = ((v.z & 0x7FFFFFFFu) >= t) ? v.z : 0u;
    v.w = ((v.w & 0x7FFFFFFFu) >= t) ? v.w : 0u;
    reinterpret_cast<uint4*>(dst)[i] = v;
  }
}

extern "C" void kernel_launch(void* const* d_in, const int* in_sizes, int n_in,
                              void* d_out, int out_size, void* d_ws, size_t ws_size,
                              hipStream_t stream) {
  const unsigned* x = (const unsigned*)d_in[0];
  unsigned* out = (unsigned*)d_out;
  const int rows = in_sizes[0] / HW;   // 16384
  hipLaunchKernelGGL(topk_mask_kernel, dim3(rows), dim3(NT), 0, stream, x, out);
}

// Round 2
// 334.976 us; speedup vs baseline: 1.4201x; 1.4201x over previous
//
#include <hip/hip_runtime.h>

#define HW   3136   // 56*56
#define HW4  784    // uint4 vectors per row
#define KSEL 313    // int(0.1 * 3136)
#define NT   256

__global__ __launch_bounds__(NT, 8)
void topk_mask_kernel(const uint4* __restrict__ x, uint4* __restrict__ out) {
  __shared__ unsigned hist[256];
  __shared__ unsigned red[4];
  __shared__ unsigned sel[4];   // [0]=bin/flag, [1]=rank-in-bin, [2]=t, [3]=idx_cut
  __shared__ unsigned glist[64];
  __shared__ unsigned ilist[64];
  __shared__ unsigned gcnt;

  const int tid  = threadIdx.x;
  const int lane = tid & 63;
  const int wv   = tid >> 6;
  const size_t row = blockIdx.x;
  const uint4* __restrict__ src = x + row * (size_t)HW4;
  uint4* __restrict__ dst = out + row * (size_t)HW4;

  // ---- row resident in registers: vectors tid, tid+256, tid+512, (tid<16: 768+tid) ----
  uint4 d[4];
  d[0] = src[tid];
  d[1] = src[tid + 256];
  d[2] = src[tid + 512];
  d[3] = (tid < 16) ? src[768 + tid] : make_uint4(0u, 0u, 0u, 0u);  // pad = 0 (below bracket)

  hist[tid] = 0u;
  if (tid == 0) { gcnt = 0u; sel[0] = 0xFFFFFFFFu; }
  __syncthreads();

  // block-wide count of keys >= v (uniform result); never call with v==0 (padding!)
  auto count_ge = [&](unsigned v) -> unsigned {
    unsigned c = 0;
#pragma unroll
    for (int q = 0; q < 4; ++q) {
      c += ((d[q].x & 0x7FFFFFFFu) >= v);
      c += ((d[q].y & 0x7FFFFFFFu) >= v);
      c += ((d[q].z & 0x7FFFFFFFu) >= v);
      c += ((d[q].w & 0x7FFFFFFFu) >= v);
    }
#pragma unroll
    for (int off = 32; off > 0; off >>= 1) c += __shfl_xor(c, off);
    __syncthreads();
    if (lane == 0) red[wv] = c;
    __syncthreads();
    return red[0] + red[1] + red[2] + red[3];
  };
  // block-wide count of (key == t && gidx <= m)
  auto count_eq_le = [&](unsigned t, unsigned m) -> unsigned {
    unsigned c = 0;
#pragma unroll
    for (int q = 0; q < 4; ++q) {
      const unsigned vec = (q < 3) ? (unsigned)(tid + (q << 8)) : (unsigned)(768 + tid);
      const unsigned e0 = vec * 4u;
      c += (((d[q].x & 0x7FFFFFFFu) == t) && (e0 + 0u <= m));
      c += (((d[q].y & 0x7FFFFFFFu) == t) && (e0 + 1u <= m));
      c += (((d[q].z & 0x7FFFFFFFu) == t) && (e0 + 2u <= m));
      c += (((d[q].w & 0x7FFFFFFFu) == t) && (e0 + 3u <= m));
    }
#pragma unroll
    for (int off = 32; off > 0; off >>= 1) c += __shfl_xor(c, off);
    __syncthreads();
    if (lane == 0) red[wv] = c;
    __syncthreads();
    return red[0] + red[1] + red[2] + red[3];
  };

  // ---- pass 1: histogram of |x| over linear buckets in [1.3, 2.0) (from registers) ----
  // bucket 0: |x| < 1.3 (surely below threshold); bucket 255: |x| >= 2.0
  const float LB = 1.3f;
  const float SC = 254.0f / 0.7f;
#pragma unroll
  for (int q = 0; q < 4; ++q) {
#pragma unroll
    for (int j = 0; j < 4; ++j) {
      unsigned key = ((j == 0) ? d[q].x : (j == 1) ? d[q].y : (j == 2) ? d[q].z : d[q].w) & 0x7FFFFFFFu;
      float a = __uint_as_float(key);
      if (a >= LB) {
        int b = 1 + (int)((fminf(a, 2.1f) - LB) * SC);
        b = (b > 255) ? 255 : b;
        atomicAdd(&hist[b], 1u);
      }
    }
  }
  __syncthreads();

  // ---- suffix scan S[b] = count(bucket >= b); find crossing bin for kr ----
  const unsigned kr = KSEL;
  unsigned c  = (tid == 0) ? 0u : hist[tid];
  unsigned sv = c;
#pragma unroll
  for (int off = 1; off < 64; off <<= 1) {
    unsigned u = __shfl_down(sv, off);
    if (lane + off < 64) sv += u;
  }
  if (lane == 0) red[wv] = sv;
  __syncthreads();
  unsigned S = sv;
  for (int w = wv + 1; w < 4; ++w) S += red[w];
  unsigned S1 = S - c;
  if (tid >= 1 && S >= kr && S1 < kr) {   // unique crossing bin
    sel[0] = (unsigned)tid;               // b*
    sel[1] = kr - S1;                     // rank needed inside bin (>=1)
  }
  __syncthreads();

  unsigned t = 0u, idx_cut = 0xFFFFFFFFu;
  bool fast = (sel[0] != 0xFFFFFFFFu);
  if (fast) {
    const unsigned bsel = sel[0];
    const unsigned krb  = sel[1];
    // ---- gather threshold-bin members (expected 2-3) with their global indices ----
#pragma unroll
    for (int q = 0; q < 4; ++q) {
      const unsigned vec = (q < 3) ? (unsigned)(tid + (q << 8)) : (unsigned)(768 + tid);
#pragma unroll
      for (int j = 0; j < 4; ++j) {
        unsigned key = ((j == 0) ? d[q].x : (j == 1) ? d[q].y : (j == 2) ? d[q].z : d[q].w) & 0x7FFFFFFFu;
        float a = __uint_as_float(key);
        if (a >= LB) {
          int b = 1 + (int)((fminf(a, 2.1f) - LB) * SC);
          b = (b > 255) ? 255 : b;
          if ((unsigned)b == bsel) {
            unsigned p = atomicAdd(&gcnt, 1u);
            if (p < 64u) { glist[p] = key; ilist[p] = vec * 4u + (unsigned)j; }
          }
        }
      }
    }
    __syncthreads();
    const unsigned cnt = gcnt;
    if (cnt <= 64u) {
      // ---- wave 0: exact threshold key + stable index cut via shuffle rank ----
      if (tid < 64) {
        unsigned kv = (tid < (int)cnt) ? glist[tid] : 0u;
        unsigned gi = (tid < (int)cnt) ? ilist[tid] : 0xFFFFFFFFu;
        unsigned gt = 0, eq = 0;
        for (int i = 0; i < (int)cnt; ++i) {
          unsigned u = __shfl(kv, i);
          gt += (u > kv) ? 1u : 0u;
          eq += (u == kv) ? 1u : 0u;
        }
        // lanes holding the k-th largest key: gt < krb <= gt+eq  (cnt >= krb guaranteed)
        if (tid < (int)cnt && gt < krb && gt + eq >= krb) {
          unsigned need = krb - gt;            // how many equals to keep (lowest indices win)
          unsigned r = 0;                      // rank of my index among equal keys
          for (int i = 0; i < (int)cnt; ++i) {
            unsigned u  = __shfl(kv, i);
            unsigned g2 = __shfl(gi, i);
            r += (u == kv && g2 < gi) ? 1u : 0u;
          }
          if (r == need - 1u) { sel[2] = kv; sel[3] = gi; }   // exactly one lane
        }
      }
      __syncthreads();
      t = sel[2]; idx_cut = sel[3];
    } else {
      fast = false;
    }
  }

  if (!fast) {
    // ---- correct-for-anything fallback: bisection on key space, then on index ----
    unsigned lo = 0u, hi = 0x80000000u;
    while (hi - lo > 1u) {
      unsigned mid = lo + ((hi - lo) >> 1);
      if (count_ge(mid) >= KSEL) lo = mid; else hi = mid;
    }
    t = lo;
    if (t == 0u) {
      idx_cut = 0xFFFFFFFFu;                   // fewer than K nonzeros: keep everything
    } else {
      unsigned cgt = (t >= 0x7FFFFFFFu) ? 0u : count_ge(t + 1u);
      unsigned need_eq = KSEL - cgt;           // >= 1
      unsigned ilo = 0u, ihi = HW - 1u;        // smallest m with count(key==t, idx<=m) >= need_eq
      while (ilo < ihi) {
        unsigned im = (ilo + ihi) >> 1;
        if (count_eq_le(t, im) >= need_eq) ihi = im; else ilo = im + 1u;
      }
      idx_cut = ilo;
    }
  }

  // ---- output from registers: keep iff key > t, or key == t and index <= idx_cut ----
#pragma unroll
  for (int q = 0; q < 4; ++q) {
    const unsigned vec = (q < 3) ? (unsigned)(tid + (q << 8)) : (unsigned)(768 + tid);
    const unsigned e0 = vec * 4u;
    uint4 v = d[q];
    unsigned k0 = v.x & 0x7FFFFFFFu, k1 = v.y & 0x7FFFFFFFu;
    unsigned k2 = v.z & 0x7FFFFFFFu, k3 = v.w & 0x7FFFFFFFu;
    v.x = (k0 > t || (k0 == t && e0 + 0u <= idx_cut)) ? v.x : 0u;
    v.y = (k1 > t || (k1 == t && e0 + 1u <= idx_cut)) ? v.y : 0u;
    v.z = (k2 > t || (k2 == t && e0 + 2u <= idx_cut)) ? v.z : 0u;
    v.w = (k3 > t || (k3 == t && e0 + 3u <= idx_cut)) ? v.w : 0u;
    if (q < 3)            dst[tid + (q << 8)] = v;
    else if (tid < 16)    dst[768 + tid]      = v;
  }
}

extern "C" void kernel_launch(void* const* d_in, const int* in_sizes, int n_in,
                              void* d_out, int out_size, void* d_ws, size_t ws_size,
                              hipStream_t stream) {
  const uint4* x = (const uint4*)d_in[0];
  uint4* out = (uint4*)d_out;
  const int rows = in_sizes[0] / HW;   // 16384
  hipLaunchKernelGGL(topk_mask_kernel, dim3(rows), dim3(NT), 0, stream, x, out);
}